// Round 6
// baseline (716.869 us; speedup 1.0000x reference)
//
#include <hip/hip_runtime.h>

#define RNN_B 256
#define RNN_T 2048
#define RNN_IN 64
#define RNN_N 32
#define RNN_O 32
#define RNN_R 6
#define RNN_ALPHA 0.1f
#define KSCALE 2.8853900817779268f   /* 2*log2(e): folded into cm and xp */
#define CHUNK 64
#define NCH (RNN_T / CHUNK)          /* 32 chunks */

// ---------------------------------------------------------------------------
// Cross-lane helpers: all-VALU (DPP / permlane), no LDS pipe.
// ---------------------------------------------------------------------------
template <int CTRL>
__device__ __forceinline__ float dpp_add(float v) {
    int t = __builtin_amdgcn_update_dpp(0, __float_as_int(v), CTRL, 0xf, 0xf, true);
    return v + __int_as_float(t);
}

// v[i] + v[i^32] in every lane: one permlane32_swap (both outputs used) + add.
__device__ __forceinline__ float xsum32(float v) {
#if __has_builtin(__builtin_amdgcn_permlane32_swap)
    typedef int v2i __attribute__((ext_vector_type(2)));
    v2i r = __builtin_amdgcn_permlane32_swap(__float_as_int(v),
                                             __float_as_int(v), false, false);
    return __int_as_float(r.x) + __int_as_float(r.y);
#else
    return v + __shfl_xor(v, 32, 64);
#endif
}
// v[i] + v[i^16] in every lane.
__device__ __forceinline__ float xsum16(float v) {
#if __has_builtin(__builtin_amdgcn_permlane16_swap)
    typedef int v2i __attribute__((ext_vector_type(2)));
    v2i r = __builtin_amdgcn_permlane16_swap(__float_as_int(v),
                                             __float_as_int(v), false, false);
    return __int_as_float(r.x) + __int_as_float(r.y);
#else
    return v + __shfl_xor(v, 16, 64);
#endif
}

__device__ __forceinline__ float fast_exp2(float x) {
#if __has_builtin(__builtin_amdgcn_exp2f)
    return __builtin_amdgcn_exp2f(x);
#else
    return __expf(x * 0.6931471805599453f);
#endif
}
__device__ __forceinline__ float fast_rcp(float x) {
#if __has_builtin(__builtin_amdgcn_rcpf)
    return __builtin_amdgcn_rcpf(x);
#else
    return __frcp_rn(x);
#endif
}

// ---------------------------------------------------------------------------
// Fused kernel: one block (256 thr = 4 waves) per batch sequence.
//   wave 1: x-projection producer  — chunk c+1 -> xp_lds[(c+1)&1]
//   wave 0: recurrence scan        — chunk c   : xp_lds[c&1] -> h_lds[c&1]
//   wave 2: output projection      — chunk c-1 : h_lds[(c-1)&1] -> y (global)
//   wave 3: idle (barrier participant)
// One __syncthreads per chunk; double buffers keep writer/reader on opposite
// parities at every phase. The scan loop touches NO global memory and has no
// vmcnt waits; its only memory ops are 1 ds_read_b32 + 1 ds_write_b32 /step.
// h history never goes to HBM (only y and h_final are outputs).
// Numerics identical to the previous 3-kernel version (same formulas/order).
// ---------------------------------------------------------------------------
__global__ __launch_bounds__(256, 1) void k_fused(
    const float* __restrict__ u, const float* __restrict__ W_in,
    const float* __restrict__ bias,
    const float* __restrict__ m, const float* __restrict__ nvec,
    const float* __restrict__ Mmat, const float* __restrict__ Nmat,
    const float* __restrict__ W_out, const float* __restrict__ b_out,
    float* __restrict__ yout, float* __restrict__ hfin)
{
    __shared__ __align__(16) float xp_lds[2][CHUNK][RNN_N];
    __shared__ __align__(16) float h_lds[2][CHUNK][RNN_N];

    const int b    = blockIdx.x;
    const int tid  = threadIdx.x;
    const int wid  = tid >> 6;
    const int lane = tid & 63;

    // ---- wave-0 recurrence state (2x2 lane decomposition) ----
    // k = lane&15, q = rank group (0: ranks 0..3, 1: ranks 4..6+pad),
    // p = element parity; lane owns hidden element e = 2k+p.
    const int k = lane & 15;
    const int q = (lane >> 4) & 1;
    const int p = lane >> 5;
    const int e = 2 * k + p;

    float cn[4] = {0.f, 0.f, 0.f, 0.f}, cm[4] = {0.f, 0.f, 0.f, 0.f};
    if (wid == 0) {
        #pragma unroll
        for (int j = 0; j < 4; ++j) {
            const int r = 4 * q + j;
            float cnv = 0.f, cmv = 0.f;
            if (r == 0)          { cnv = nvec[e];              cmv = m[e]; }
            else if (r <= RNN_R) { cnv = Nmat[e*RNN_R + (r-1)]; cmv = Mmat[e*RNN_R + (r-1)]; }
            cn[j] = cnv;
            cm[j] = KSCALE * cmv;
        }
    }
    float h = 0.0f;
    const bool hst = (wid == 0) && (q == 0);   // 32 lanes cover e = 0..31

    for (int ph = 0; ph < NCH + 2; ++ph) {
        if (wid == 1 && ph < NCH) {
            // ---- producer: xp for chunk ph, one t-row per lane ----
            const int t = ph * CHUNK + lane;
            const float4* __restrict__ u4 =
                reinterpret_cast<const float4*>(u) +
                ((size_t)b * RNN_T + t) * (RNN_IN / 4);
            float acc[RNN_N];
            #pragma unroll
            for (int n = 0; n < RNN_N; ++n) acc[n] = bias[n];
            #pragma unroll
            for (int qq = 0; qq < RNN_IN / 4; ++qq) {
                const float4 v = u4[qq];
                #pragma unroll
                for (int n = 0; n < RNN_N; ++n) {
                    const float* wr = W_in + n * RNN_IN + 4 * qq; // uniform
                    acc[n] = fmaf(wr[0], v.x, acc[n]);
                    acc[n] = fmaf(wr[1], v.y, acc[n]);
                    acc[n] = fmaf(wr[2], v.z, acc[n]);
                    acc[n] = fmaf(wr[3], v.w, acc[n]);
                }
            }
            float4* dst = reinterpret_cast<float4*>(&xp_lds[ph & 1][lane][0]);
            #pragma unroll
            for (int qq = 0; qq < RNN_N / 4; ++qq)
                dst[qq] = make_float4(KSCALE * acc[4*qq+0], KSCALE * acc[4*qq+1],
                                      KSCALE * acc[4*qq+2], KSCALE * acc[4*qq+3]);
        } else if (wid == 0 && ph >= 1 && ph <= NCH) {
            // ---- scan: chunk ph-1 ----
            const int buf = (ph - 1) & 1;
            const float* __restrict__ xrow = &xp_lds[buf][0][e];
            float*       __restrict__ hrow = &h_lds[buf][0][e];
            #pragma unroll 8
            for (int tl = 0; tl < CHUNK; ++tl) {
                // LDS read issued at step top; consumed after the tree (~200cy)
                const float xe = xrow[tl * RNN_N];

                // 4 products + 4 interleaved 16-lane DPP trees.
                float s0 = cn[0]*h, s1 = cn[1]*h, s2 = cn[2]*h, s3 = cn[3]*h;
                s0 = dpp_add<0xB1>(s0);  s1 = dpp_add<0xB1>(s1);
                s2 = dpp_add<0xB1>(s2);  s3 = dpp_add<0xB1>(s3);
                s0 = dpp_add<0x4E>(s0);  s1 = dpp_add<0x4E>(s1);
                s2 = dpp_add<0x4E>(s2);  s3 = dpp_add<0x4E>(s3);
                s0 = dpp_add<0x141>(s0); s1 = dpp_add<0x141>(s1);
                s2 = dpp_add<0x141>(s2); s3 = dpp_add<0x141>(s3);
                s0 = dpp_add<0x140>(s0); s1 = dpp_add<0x140>(s1);
                s2 = dpp_add<0x140>(s2); s3 = dpp_add<0x140>(s3);

                // Parity combine -> full 32-element rank sums.
                s0 = xsum32(s0); s1 = xsum32(s1); s2 = xsum32(s2); s3 = xsum32(s3);

                // Rank fold for my element, then rank-group combine (lane^16).
                float w = fmaf(cm[1], s1, cm[0]*s0) + fmaf(cm[3], s3, cm[2]*s2);
                w = xsum16(w);
                const float z = w + xe;

                // tanh via exp2: h' = (0.9h + 0.1) - 0.2*rcp(exp2(z)+1)
                const float ez = fast_exp2(z);
                const float g  = fmaf(1.0f - RNN_ALPHA, h, RNN_ALPHA);
                h = fmaf(-2.0f * RNN_ALPHA, fast_rcp(ez + 1.0f), g);

                if (hst) hrow[tl * RNN_N] = h;   // 32 lanes, 32 banks
            }
        } else if (wid == 2 && ph >= 2) {
            // ---- drain: y projection for chunk ph-2, one t-row per lane ----
            const int ch = ph - 2;
            const int t  = ch * CHUNK + lane;
            const float4* __restrict__ hr =
                reinterpret_cast<const float4*>(&h_lds[ch & 1][lane][0]);
            float y[RNN_O];
            #pragma unroll
            for (int o = 0; o < RNN_O; ++o) y[o] = b_out[o];
            #pragma unroll
            for (int qq = 0; qq < RNN_N / 4; ++qq) {
                const float4 v = hr[qq];
                #pragma unroll
                for (int o = 0; o < RNN_O; ++o) {
                    const float* wr = W_out + o * RNN_N + 4 * qq; // uniform
                    y[o] = fmaf(wr[0], v.x, y[o]);
                    y[o] = fmaf(wr[1], v.y, y[o]);
                    y[o] = fmaf(wr[2], v.z, y[o]);
                    y[o] = fmaf(wr[3], v.w, y[o]);
                }
            }
            float4* q4 = reinterpret_cast<float4*>(yout) +
                         ((size_t)b * RNN_T + t) * (RNN_N / 4);
            #pragma unroll
            for (int qq = 0; qq < RNN_N / 4; ++qq)
                q4[qq] = make_float4(y[4*qq+0], y[4*qq+1], y[4*qq+2], y[4*qq+3]);
        }
        __syncthreads();
    }

    if (hst) hfin[b * RNN_N + e] = h;
}

extern "C" void kernel_launch(void* const* d_in, const int* in_sizes, int n_in,
                              void* d_out, int out_size, void* d_ws, size_t ws_size,
                              hipStream_t stream)
{
    const float* u     = (const float*)d_in[0];  // [256,2048,64]
    const float* W_in  = (const float*)d_in[1];  // [32,64]
    const float* m     = (const float*)d_in[2];  // [32,1]
    const float* nvec  = (const float*)d_in[3];  // [32,1]
    const float* Mmat  = (const float*)d_in[4];  // [32,6]
    const float* Nmat  = (const float*)d_in[5];  // [32,6]
    const float* bias  = (const float*)d_in[6];  // [32]
    const float* W_out = (const float*)d_in[7];  // [32,32]
    const float* b_out = (const float*)d_in[8];  // [32]
    float* out = (float*)d_out;                  // outputs [256,2048,32] ++ h_final [256,32]

    float* hfin = out + (size_t)RNN_B * RNN_T * RNN_N;

    k_fused<<<RNN_B, 256, 0, stream>>>(u, W_in, bias, m, nvec, Mmat, Nmat,
                                       W_out, b_out, out, hfin);
}

// Round 13
// 615.581 us; speedup vs baseline: 1.1645x; 1.1645x over previous
//
#include <hip/hip_runtime.h>

#define RNN_B 256
#define RNN_T 2048
#define RNN_IN 64
#define RNN_N 32
#define RNN_O 32
#define RNN_R 6
#define RNN_ALPHA 0.1f
#define KSCALE 2.8853900817779268f   /* 2*log2(e): folded into cm and xp */

// ---------------------------------------------------------------------------
// Kernel 1: xp[row][n] = KSCALE * (bias[n] + sum_i W_in[n][i] * u[row][i])
// LDS-transpose staging: block of 256 threads handles 256 rows.
//   P1: coalesced load of 256x64 floats (4096 f4, lane-adjacent) -> LDS,
//       f4-slot swizzle q^(row&15) (writes stay float4).
//   P2: thread t computes row t from LDS (reads slot qq^sw -> chunk qq).
//   P3: results -> LDS (swizzle q^(row&7)), P4: coalesced store 2048 f4.
// Fixes the 256B-stride lane scatter (64 segments/instr) of the naive form.
// ---------------------------------------------------------------------------
__global__ __launch_bounds__(256) void k_xproj(
    const float* __restrict__ u, const float* __restrict__ W_in,
    const float* __restrict__ bias, float* __restrict__ xp)
{
    __shared__ float4 lds[4096];                 // 64 KB, dual-purpose
    const int tid = threadIdx.x;
    const size_t row0 = (size_t)blockIdx.x * 256;

    // P1: stage u rows [row0, row0+256), fully coalesced.
    const float4* __restrict__ u4 =
        reinterpret_cast<const float4*>(u) + row0 * (RNN_IN / 4);
    #pragma unroll
    for (int j = 0; j < 16; ++j) {
        const int g   = tid + j * 256;           // 0..4095
        const int row = g >> 4, q = g & 15;
        lds[row * 16 + (q ^ (row & 15))] = u4[g];
    }
    __syncthreads();

    // P2: compute my row (t-row = tid).
    float acc[RNN_N];
    #pragma unroll
    for (int n = 0; n < RNN_N; ++n) acc[n] = bias[n];
    const int sw = tid & 15;
    #pragma unroll
    for (int qq = 0; qq < RNN_IN / 4; ++qq) {
        const float4 v = lds[tid * 16 + (qq ^ sw)];   // = u chunk qq of row tid
        #pragma unroll
        for (int n = 0; n < RNN_N; ++n) {
            const float* wr = W_in + n * RNN_IN + 4 * qq;   // uniform -> s_load
            acc[n] = fmaf(wr[0], v.x, acc[n]);
            acc[n] = fmaf(wr[1], v.y, acc[n]);
            acc[n] = fmaf(wr[2], v.z, acc[n]);
            acc[n] = fmaf(wr[3], v.w, acc[n]);
        }
    }
    __syncthreads();                              // all u reads done

    // P3: stage xp rows (8 f4/row, swizzle q^(row&7)).
    const int sw8 = tid & 7;
    #pragma unroll
    for (int q = 0; q < RNN_N / 4; ++q)
        lds[tid * 8 + (q ^ sw8)] =
            make_float4(KSCALE * acc[4*q+0], KSCALE * acc[4*q+1],
                        KSCALE * acc[4*q+2], KSCALE * acc[4*q+3]);
    __syncthreads();

    // P4: coalesced store of 2048 f4.
    float4* __restrict__ o4 =
        reinterpret_cast<float4*>(xp) + row0 * (RNN_N / 4);
    #pragma unroll
    for (int j = 0; j < 8; ++j) {
        const int g   = tid + j * 256;            // 0..2047
        const int row = g >> 3, q = g & 7;
        o4[g] = lds[row * 8 + (q ^ (row & 7))];
    }
}

// ---------------------------------------------------------------------------
// Cross-lane helpers for the scan: all-VALU (DPP / permlane), no LDS pipe.
// ---------------------------------------------------------------------------
template <int CTRL>
__device__ __forceinline__ float dpp_add(float v) {
    int t = __builtin_amdgcn_update_dpp(0, __float_as_int(v), CTRL, 0xf, 0xf, true);
    return v + __int_as_float(t);
}
__device__ __forceinline__ float xsum32(float v) {
#if __has_builtin(__builtin_amdgcn_permlane32_swap)
    typedef int v2i __attribute__((ext_vector_type(2)));
    v2i r = __builtin_amdgcn_permlane32_swap(__float_as_int(v),
                                             __float_as_int(v), false, false);
    return __int_as_float(r.x) + __int_as_float(r.y);
#else
    return v + __shfl_xor(v, 32, 64);
#endif
}
__device__ __forceinline__ float xsum16(float v) {
#if __has_builtin(__builtin_amdgcn_permlane16_swap)
    typedef int v2i __attribute__((ext_vector_type(2)));
    v2i r = __builtin_amdgcn_permlane16_swap(__float_as_int(v),
                                             __float_as_int(v), false, false);
    return __int_as_float(r.x) + __int_as_float(r.y);
#else
    return v + __shfl_xor(v, 16, 64);
#endif
}
__device__ __forceinline__ float fast_exp2(float x) {
#if __has_builtin(__builtin_amdgcn_exp2f)
    return __builtin_amdgcn_exp2f(x);
#else
    return __expf(x * 0.6931471805599453f);
#endif
}
__device__ __forceinline__ float fast_rcp(float x) {
#if __has_builtin(__builtin_amdgcn_rcpf)
    return __builtin_amdgcn_rcpf(x);
#else
    return __frcp_rn(x);
#endif
}

// ---------------------------------------------------------------------------
// Kernel 2 (UNCHANGED from the 310us Round-5 version): sequential scan,
// one wave per batch, 2x2 lane decomposition (k=lane&15 element pair,
// q=rank group, p=element parity; lane owns element e=2k+p).
// ---------------------------------------------------------------------------
__global__ __launch_bounds__(64, 1) void k_recur(
    const float* __restrict__ m, const float* __restrict__ nvec,
    const float* __restrict__ Mmat, const float* __restrict__ Nmat,
    const float* __restrict__ xp,    // [B,T,N] prescaled input projections
    float* __restrict__ hout,        // [B,T,N] hidden states (ws or out)
    float* __restrict__ hfin)
{
    const int b    = blockIdx.x;
    const int lane = threadIdx.x;
    const int k    = lane & 15;
    const int q    = (lane >> 4) & 1;    // rank group: 0 -> r 0..3, 1 -> r 4..6
    const int p    = lane >> 5;          // element parity
    const int e    = 2 * k + p;          // my hidden element

    float cn[4], cm[4];
    #pragma unroll
    for (int j = 0; j < 4; ++j) {
        const int r = 4 * q + j;
        float cnv = 0.f, cmv = 0.f;
        if (r == 0)          { cnv = nvec[e];               cmv = m[e]; }
        else if (r <= RNN_R) { cnv = Nmat[e*RNN_R + (r-1)]; cmv = Mmat[e*RNN_R + (r-1)]; }
        cn[j] = cnv;
        cm[j] = KSCALE * cmv;
    }

    const float2* __restrict__ x2 =
        reinterpret_cast<const float2*>(xp + (size_t)b * (RNN_T * RNN_N)) + k;
    float* __restrict__ hbase = hout + (size_t)b * (RNN_T * RNN_N);

    float h = 0.0f;

    const int PF = 8;
    float2 xr[PF];
    #pragma unroll
    for (int i = 0; i < PF; ++i) xr[i] = x2[i * (RNN_N / 2)];

    const bool do_store = (q == 0);

    #pragma unroll 8
    for (int t = 0; t < RNN_T; ++t) {
        const int slot = t & (PF - 1);
        const float2 xv = xr[slot];
        xr[slot] = x2[(t + PF) * (RNN_N / 2)];   // past-T lands in hfin tail
        const float xe = p ? xv.y : xv.x;

        float s0 = cn[0] * h, s1 = cn[1] * h, s2 = cn[2] * h, s3 = cn[3] * h;
        s0 = dpp_add<0xB1>(s0);  s1 = dpp_add<0xB1>(s1);
        s2 = dpp_add<0xB1>(s2);  s3 = dpp_add<0xB1>(s3);
        s0 = dpp_add<0x4E>(s0);  s1 = dpp_add<0x4E>(s1);
        s2 = dpp_add<0x4E>(s2);  s3 = dpp_add<0x4E>(s3);
        s0 = dpp_add<0x141>(s0); s1 = dpp_add<0x141>(s1);
        s2 = dpp_add<0x141>(s2); s3 = dpp_add<0x141>(s3);
        s0 = dpp_add<0x140>(s0); s1 = dpp_add<0x140>(s1);
        s2 = dpp_add<0x140>(s2); s3 = dpp_add<0x140>(s3);

        s0 = xsum32(s0); s1 = xsum32(s1); s2 = xsum32(s2); s3 = xsum32(s3);

        float w = fmaf(cm[1], s1, cm[0] * s0) + fmaf(cm[3], s3, cm[2] * s2);
        w = xsum16(w);
        const float z = w + xe;

        const float ez = fast_exp2(z);
        const float g  = fmaf(1.0f - RNN_ALPHA, h, RNN_ALPHA);
        h = fmaf(-2.0f * RNN_ALPHA, fast_rcp(ez + 1.0f), g);

        if (do_store) hbase[t * RNN_N + e] = h;
    }
    if (do_store) hfin[b * RNN_N + e] = h;
}

// ---------------------------------------------------------------------------
// Kernel 3: y[row][o] = b_out[o] + W_out[o][:]·h[row][:], LDS-transpose
// staged exactly like k_xproj (256 rows/block, 32 KB LDS, reused for both
// the h stage and the y stage). In-place safe (same rows in/out per block,
// reads complete before writes via the syncs).
// ---------------------------------------------------------------------------
__global__ __launch_bounds__(256) void k_out(
    const float* __restrict__ W_out, const float* __restrict__ b_out,
    const float* __restrict__ hsrc, float* __restrict__ ydst)
{
    __shared__ float4 lds[2048];                 // 32 KB
    const int tid = threadIdx.x;
    const size_t row0 = (size_t)blockIdx.x * 256;

    // P1: coalesced stage of h rows.
    const float4* __restrict__ h4 =
        reinterpret_cast<const float4*>(hsrc) + row0 * (RNN_N / 4);
    #pragma unroll
    for (int j = 0; j < 8; ++j) {
        const int g   = tid + j * 256;           // 0..2047
        const int row = g >> 3, q = g & 7;
        lds[row * 8 + (q ^ (row & 7))] = h4[g];
    }
    __syncthreads();

    // P2: compute my row.
    float y[RNN_O];
    #pragma unroll
    for (int o = 0; o < RNN_O; ++o) y[o] = b_out[o];
    const int sw = tid & 7;
    #pragma unroll
    for (int qq = 0; qq < RNN_N / 4; ++qq) {
        const float4 v = lds[tid * 8 + (qq ^ sw)];   // = h chunk qq of row tid
        #pragma unroll
        for (int o = 0; o < RNN_O; ++o) {
            const float* wr = W_out + o * RNN_N + 4 * qq;  // uniform -> s_load
            y[o] = fmaf(wr[0], v.x, y[o]);
            y[o] = fmaf(wr[1], v.y, y[o]);
            y[o] = fmaf(wr[2], v.z, y[o]);
            y[o] = fmaf(wr[3], v.w, y[o]);
        }
    }
    __syncthreads();                              // all h reads done

    // P3: stage y rows.
    #pragma unroll
    for (int q = 0; q < RNN_O / 4; ++q)
        lds[tid * 8 + (q ^ sw)] =
            make_float4(y[4*q+0], y[4*q+1], y[4*q+2], y[4*q+3]);
    __syncthreads();

    // P4: coalesced store.
    float4* __restrict__ o4 =
        reinterpret_cast<float4*>(ydst) + row0 * (RNN_O / 4);
    #pragma unroll
    for (int j = 0; j < 8; ++j) {
        const int g   = tid + j * 256;
        const int row = g >> 3, q = g & 7;
        o4[g] = lds[row * 8 + (q ^ (row & 7))];
    }
}

extern "C" void kernel_launch(void* const* d_in, const int* in_sizes, int n_in,
                              void* d_out, int out_size, void* d_ws, size_t ws_size,
                              hipStream_t stream)
{
    const float* u     = (const float*)d_in[0];  // [256,2048,64]
    const float* W_in  = (const float*)d_in[1];  // [32,64]
    const float* m     = (const float*)d_in[2];  // [32,1]
    const float* nvec  = (const float*)d_in[3];  // [32,1]
    const float* Mmat  = (const float*)d_in[4];  // [32,6]
    const float* Nmat  = (const float*)d_in[5];  // [32,6]
    const float* bias  = (const float*)d_in[6];  // [32]
    const float* W_out = (const float*)d_in[7];  // [32,32]
    const float* b_out = (const float*)d_in[8];  // [32]
    float* out = (float*)d_out;                  // outputs [256,2048,32] ++ h_final [256,32]

    float* hfin = out + (size_t)RNN_B * RNN_T * RNN_N;

    // h states routed through the workspace so k_recur's loads (xp, from out)
    // and stores (h, to ws) are provably non-aliasing. Fallback: in-place.
    const size_t hbytes = (size_t)RNN_B * RNN_T * RNN_N * sizeof(float);
    float* hbuf = (ws_size >= hbytes) ? (float*)d_ws : out;

    k_xproj<<<(RNN_B * RNN_T) / 256, 256, 0, stream>>>(u, W_in, bias, out);
    k_recur<<<RNN_B, 64, 0, stream>>>(m, nvec, Mmat, Nmat, out, hbuf, hfin);
    k_out  <<<(RNN_B * RNN_T) / 256, 256, 0, stream>>>(W_out, b_out, hbuf, out);
}